// Round 5
// baseline (721.557 us; speedup 1.0000x reference)
//
#include <hip/hip_runtime.h>
#include <math.h>

#define DD 5          // embedding dim
#define EST 8         // emb row stride (padded 5 -> 8 floats, 32B rows)
#define NFREQ 50      // frequencies per coordinate
#define NB 128        // sort blocks
// ENC_DIM = 4*NFREQ = 200; W row per gene = 200*5 = 1000 floats
//
// ===== ROUND 5 = MEASUREMENT PROBE =====
// embed_kernel and attn_pool_kernel carry a `reps` inflation factor (17x).
// embed repeats its pure loop; attn_pool repeats with runtime scale 0.0 on the
// first 16 passes (real gathers + real atomics adding 0.0f, numerically inert).
// Output is unchanged; durations of the two suspects are magnified 17x so the
// top-5 dispatch table exposes them by name, and the total-dur delta gives
// 16*(E+A). Best kernel remains round-2/4's; this round buys the breakdown.

// ---------------------------------------------------------------- K1: hist + out-init
__global__ __launch_bounds__(256) void hist_init_kernel(
    const int* __restrict__ gm, int F, int chunk,
    int* __restrict__ bc, int n_genes, int* __restrict__ done,
    float* __restrict__ out, const float* __restrict__ bias,
    const int* __restrict__ genes_oi, int n_cells) {
  __shared__ int cnt[1000];
  __shared__ float s_brow[1000];
  const int tid = threadIdx.x;
  if (blockIdx.x == 0 && tid == 0) *done = 0;
  for (int j = tid; j < n_genes; j += blockDim.x) {
    s_brow[j] = bias[genes_oi[j]];
    cnt[j] = 0;
  }
  __syncthreads();
  if (blockIdx.x < NB) {
    int lo = blockIdx.x * chunk;
    int hi = min(F, lo + chunk);
    for (int i = lo + tid; i < hi; i += blockDim.x)
      atomicAdd(&cnt[gm[i]], 1);
  }
  const float4* b4 = (const float4*)s_brow;
  const int q = n_genes >> 2;          // 250 float4 per row
  for (int c = blockIdx.x; c < n_cells; c += gridDim.x) {
    float4* dst = (float4*)out + (size_t)c * q;
    for (int t = tid; t < q; t += blockDim.x) dst[t] = b4[t];
  }
  __syncthreads();
  if (blockIdx.x < NB)
    for (int j = tid; j < n_genes; j += blockDim.x)
      bc[j * NB + blockIdx.x] = cnt[j];
}

// ---------------------------------------------------------------- K2: per-bin scan + starts
__global__ __launch_bounds__(256) void binscan_starts_kernel(
    int* __restrict__ bc, int n_genes, int* __restrict__ totals,
    int* __restrict__ starts, int* __restrict__ done, int nblocks) {
  __shared__ int s_amlast;
  __shared__ int s_ws[4];
  int lane = threadIdx.x & 63;
  int wv = threadIdx.x >> 6;               // 0..3
  int bin = blockIdx.x * 4 + wv;
  if (bin < n_genes) {
    int2* row = (int2*)(bc + (size_t)bin * NB);   // 64 int2 per row
    int2 v = row[lane];
    int p = v.x + v.y;
    int ip = p;
#pragma unroll
    for (int off = 1; off < 64; off <<= 1) {
      int q = __shfl_up(ip, off);
      if (lane >= off) ip += q;
    }
    int base = ip - p;                      // exclusive prefix of this lane's pair
    int2 e;
    e.x = base;
    e.y = base + v.x;
    row[lane] = e;
    if (lane == 63) totals[bin] = ip;
  }
  __syncthreads();
  if (threadIdx.x == 0) {
    __threadfence();                        // publish totals
    int tk = atomicAdd(done, 1);
    s_amlast = (tk == nblocks - 1);
  }
  __syncthreads();
  if (!s_amlast) return;
  __threadfence();                          // acquire all totals
  int t = threadIdx.x;
  int4 v = make_int4(0, 0, 0, 0);
  if (4 * t < n_genes) v = ((const int4*)totals)[t];
  int p = v.x + v.y + v.z + v.w;
  int ip = p;
#pragma unroll
  for (int off = 1; off < 64; off <<= 1) {
    int q = __shfl_up(ip, off);
    if (lane >= off) ip += q;
  }
  if (lane == 63) s_ws[wv] = ip;
  __syncthreads();
  int add = 0;
#pragma unroll
  for (int i = 0; i < 4; ++i)
    if (i < wv) add += s_ws[i];
  int excl = add + ip - p;
  int4 e;
  e.x = excl;
  e.y = excl + v.x;
  e.z = e.y + v.y;
  e.w = e.z + v.z;
  if (4 * t < n_genes) ((int4*)starts)[t] = e;
  if (4 * t + 4 == n_genes) starts[n_genes] = e.w + v.w;   // grand total
}

// ---------------------------------------------------------------- K3: scatter by gene
__global__ __launch_bounds__(256) void blockscatter_kernel(
    const int* __restrict__ gm, int F, int chunk,
    const int* __restrict__ bc, const int* __restrict__ starts,
    int* __restrict__ order, int n_genes) {
  __shared__ int cur[1000];
  int b = blockIdx.x;
  for (int j = threadIdx.x; j < n_genes; j += blockDim.x)
    cur[j] = starts[j] + bc[j * NB + b];
  __syncthreads();
  int lo = b * chunk;
  int hi = min(F, lo + chunk);
  for (int i = lo + threadIdx.x; i < hi; i += blockDim.x) {
    int g = gm[i];
    int p = atomicAdd(&cur[g], 1);
    order[p] = i;
  }
}

// ---------------------------------------------------------------- K4: fragment embedding (x reps)
__global__ __launch_bounds__(256) void embed_kernel(
    const float2* __restrict__ coords, const int* __restrict__ order,
    const int* __restrict__ starts, const float* __restrict__ W,
    float* __restrict__ emb, int n_genes, int reps) {
  __shared__ float s_w[1000];
  __shared__ float s_freq[NFREQ];
  const int tid = threadIdx.x;
  if (tid < NFREQ)
    s_freq[tid] = exp2f(-0.39863137f * (float)(tid + 1));
  int g = blockIdx.x;
  const float* __restrict__ Wg = W + (size_t)g * (4 * NFREQ * DD);
  for (int idx = tid; idx < 1000; idx += blockDim.x) {
    int k = idx / 20, r = idx % 20;
    s_w[idx] = (r < 10) ? Wg[10 * k + r] : Wg[500 + 10 * k + (r - 10)];
  }
  __syncthreads();
  int s0 = starts[g];
  int s1 = starts[g + 1];
  const float4* __restrict__ w4 = (const float4*)s_w;

  for (int rep = 0; rep < reps; ++rep) {
    for (int i = s0 + tid; i < s1; i += blockDim.x) {
      int f = order[i];
      float2 xy = coords[f];
      float a0 = 0.f, a1 = 0.f, a2 = 0.f, a3 = 0.f, a4 = 0.f;
#pragma unroll 2
      for (int k = 0; k < NFREQ; ++k) {
        float fr = s_freq[k];
        float ax = xy.x * fr;
        float ay = xy.y * fr;
        float sx = __sinf(ax), cx = __cosf(ax);
        float sy = __sinf(ay), cy = __cosf(ay);
        float4 c0 = w4[5 * k + 0];
        float4 c1 = w4[5 * k + 1];
        float4 c2 = w4[5 * k + 2];
        float4 c3 = w4[5 * k + 3];
        float4 c4 = w4[5 * k + 4];
        a0 += sx * c0.x + cx * c1.y + sy * c2.z + cy * c3.w;
        a1 += sx * c0.y + cx * c1.z + sy * c2.w + cy * c4.x;
        a2 += sx * c0.z + cx * c1.w + sy * c3.x + cy * c4.y;
        a3 += sx * c0.w + cx * c2.x + sy * c3.y + cy * c4.z;
        a4 += sx * c1.x + cx * c2.y + sy * c3.z + cy * c4.w;
      }
      float* e = emb + (size_t)f * EST;
      float4 r;
      r.x = 1.f / (1.f + __expf(-a0));
      r.y = 1.f / (1.f + __expf(-a1));
      r.z = 1.f / (1.f + __expf(-a2));
      r.w = 1.f / (1.f + __expf(-a3));
      *reinterpret_cast<float4*>(e) = r;
      e[4] = 1.f / (1.f + __expf(-a4));
    }
  }
}

// ---------------------------------------------------------------- attention group, DELTA pool
template <int SZ>
__device__ __forceinline__ void attn_group_delta(const int* __restrict__ idx,
                                                 const float* __restrict__ emb,
                                                 const int* __restrict__ lci,
                                                 const int* __restrict__ genes_oi,
                                                 const float* __restrict__ wexpr,
                                                 int n_genes, float* __restrict__ out,
                                                 float sc_out) {
  int fid[SZ];
  float x[SZ][DD];
#pragma unroll
  for (int a = 0; a < SZ; ++a) {
    fid[a] = idx[a];
    const float* p = emb + (size_t)fid[a] * EST;
    float4 v = *reinterpret_cast<const float4*>(p);
    x[a][0] = v.x; x[a][1] = v.y; x[a][2] = v.z; x[a][3] = v.w;
    x[a][4] = p[4];
  }
  const float scale = rsqrtf((float)SZ);   // reference scales by sqrt(seq_len)
#pragma unroll
  for (int a = 0; a < SZ; ++a) {
    float sc[SZ];
    float m = -1e30f;
#pragma unroll
    for (int b = 0; b < SZ; ++b) {
      float dt = 0.f;
#pragma unroll
      for (int d = 0; d < DD; ++d) dt += x[a][d] * x[b][d];
      sc[b] = dt * scale;
      m = fmaxf(m, sc[b]);
    }
    float sum = 0.f;
#pragma unroll
    for (int b = 0; b < SZ; ++b) {
      sc[b] = __expf(sc[b] - m);
      sum += sc[b];
    }
    float inv = 1.f / sum;
    int ix = lci[fid[a]];
    int g = genes_oi[ix % n_genes];
    const float* w = wexpr + (size_t)g * DD;
    float s = 0.f;
#pragma unroll
    for (int d = 0; d < DD; ++d) {
      float acc = 0.f;
#pragma unroll
      for (int b = 0; b < SZ; ++b) acc += sc[b] * x[b][d];
      s += (acc * inv - x[a][d]) * w[d];
    }
    atomicAdd(out + ix, s * sc_out);
  }
}

// ---------------------------------------------------------------- K5: attention + pool-all (x reps)
// First reps-1 passes use runtime zero scale: identical gathers + atomics,
// numerically inert. Last pass uses 1.0f.
__global__ __launch_bounds__(256) void attn_pool_kernel(
    const int* __restrict__ n2, int g2,
    const int* __restrict__ n3, int g3,
    const int* __restrict__ n4, int g4,
    const float* __restrict__ emb, const int* __restrict__ lci,
    const int* __restrict__ genes_oi, const float* __restrict__ wexpr,
    int F, int n_genes, float* __restrict__ out, int reps, float zero) {
  int gtid = blockIdx.x * blockDim.x + threadIdx.x;
  int gs = gridDim.x * blockDim.x;
  int gtot = g2 + g3 + g4;
  for (int rep = 0; rep < reps; ++rep) {
    float sc_out = (rep == reps - 1) ? 1.0f : zero;
    for (int w = gtid; w < gtot; w += gs) {
      if (w < g2)
        attn_group_delta<2>(n2 + (size_t)w * 2, emb, lci, genes_oi, wexpr, n_genes, out, sc_out);
      else if (w < g2 + g3)
        attn_group_delta<3>(n3 + (size_t)(w - g2) * 3, emb, lci, genes_oi, wexpr, n_genes, out, sc_out);
      else
        attn_group_delta<4>(n4 + (size_t)(w - g2 - g3) * 4, emb, lci, genes_oi, wexpr, n_genes, out, sc_out);
    }
    for (int f = gtid; f < F; f += gs) {
      int ix = lci[f];
      int g = genes_oi[ix % n_genes];
      const float* e = emb + (size_t)f * EST;
      float4 v = *reinterpret_cast<const float4*>(e);
      const float* w = wexpr + (size_t)g * DD;
      float s = v.x * w[0] + v.y * w[1] + v.z * w[2] + v.w * w[3] + e[4] * w[4];
      atomicAdd(out + ix, s * sc_out);
    }
  }
}

// ---------------------------------------------------------------- launch
extern "C" void kernel_launch(void* const* d_in, const int* in_sizes, int n_in,
                              void* d_out, int out_size, void* d_ws, size_t ws_size,
                              hipStream_t stream) {
  const float2* coords  = (const float2*)d_in[0];
  const int* gm         = (const int*)d_in[1];
  const int* n2         = (const int*)d_in[2];
  const int* n3         = (const int*)d_in[3];
  const int* n4         = (const int*)d_in[4];
  const int* lci        = (const int*)d_in[5];
  const int* genes_oi   = (const int*)d_in[6];
  const float* W        = (const float*)d_in[7];
  const float* wexpr    = (const float*)d_in[8];
  const float* bias     = (const float*)d_in[9];
  float* out            = (float*)d_out;

  const int F       = in_sizes[1];
  const int n_genes = in_sizes[6];
  const int g2 = in_sizes[2] / 2;
  const int g3 = in_sizes[3] / 3;
  const int g4 = in_sizes[4] / 4;

  char* ws = (char*)d_ws;
  size_t off = 0;
  float* emb   = (float*)(ws + off); off += (size_t)F * EST * sizeof(float);
  int* order   = (int*)(ws + off);   off += (size_t)F * sizeof(int);
  int* bc      = (int*)(ws + off);   off += (size_t)n_genes * NB * sizeof(int);
  off = (off + 15) & ~(size_t)15;
  int* starts  = (int*)(ws + off);   off += (size_t)(n_genes + 4) * sizeof(int);
  off = (off + 15) & ~(size_t)15;
  int* totals  = (int*)(ws + off);   off += (size_t)n_genes * sizeof(int);
  int* done    = (int*)(ws + off);   off += 4 * sizeof(int);

  const int tb = 256;
  const int chunk = (F + NB - 1) / NB;
  const int n_cells = out_size / n_genes;   // out_size in floats

  const int REPS = 17;                      // probe inflation factor

  hist_init_kernel<<<1024, tb, 0, stream>>>(gm, F, chunk, bc, n_genes, done,
                                            out, bias, genes_oi, n_cells);
  int scan_blocks = (n_genes + 3) / 4;    // one wave per bin, 4 bins/block
  binscan_starts_kernel<<<scan_blocks, tb, 0, stream>>>(bc, n_genes, totals,
                                                        starts, done, scan_blocks);
  blockscatter_kernel<<<NB, tb, 0, stream>>>(gm, F, chunk, bc, starts, order, n_genes);
  embed_kernel<<<n_genes, tb, 0, stream>>>(coords, order, starts, W, emb, n_genes, REPS);
  attn_pool_kernel<<<1024, tb, 0, stream>>>(n2, g2, n3, g3, n4, g4,
                                            emb, lci, genes_oi, wexpr,
                                            F, n_genes, out, REPS, 0.0f);
}

// Round 6
// 138.020 us; speedup vs baseline: 5.2279x; 5.2279x over previous
//
#include <hip/hip_runtime.h>
#include <math.h>

#define DD 5          // embedding dim
#define EST 8         // emb row stride (padded 5 -> 8 floats, 32B rows)
#define NFREQ 50      // frequencies per coordinate
#define NB 128        // sort blocks
// ENC_DIM = 4*NFREQ = 200; W row per gene = 200*5 = 1000 floats
//
// Measured budget (r5 inflation probe): attn_pool A=20.9us, embed E=15.0us,
// sort trio + init ~15us modeled, ~95us stable harness floor (poison fills).
// r6: raw pool fused into embed (delta-pool makes it exact); K5 = groups only.

// ---------------------------------------------------------------- K1: hist + out-init
__global__ __launch_bounds__(256) void hist_init_kernel(
    const int* __restrict__ gm, int F, int chunk,
    int* __restrict__ bc, int n_genes, int* __restrict__ done,
    float* __restrict__ out, const float* __restrict__ bias,
    const int* __restrict__ genes_oi, int n_cells) {
  __shared__ int cnt[1000];
  __shared__ float s_brow[1000];
  const int tid = threadIdx.x;
  if (blockIdx.x == 0 && tid == 0) *done = 0;
  for (int j = tid; j < n_genes; j += blockDim.x) {
    s_brow[j] = bias[genes_oi[j]];
    cnt[j] = 0;
  }
  __syncthreads();
  if (blockIdx.x < NB) {
    int lo = blockIdx.x * chunk;
    int hi = min(F, lo + chunk);
    for (int i = lo + tid; i < hi; i += blockDim.x)
      atomicAdd(&cnt[gm[i]], 1);
  }
  // out <- bias row broadcast: pure float4 stores from LDS (n_genes % 4 == 0)
  const float4* b4 = (const float4*)s_brow;
  const int q = n_genes >> 2;          // 250 float4 per row
  for (int c = blockIdx.x; c < n_cells; c += gridDim.x) {
    float4* dst = (float4*)out + (size_t)c * q;
    for (int t = tid; t < q; t += blockDim.x) dst[t] = b4[t];
  }
  __syncthreads();
  if (blockIdx.x < NB)
    for (int j = tid; j < n_genes; j += blockDim.x)
      bc[j * NB + blockIdx.x] = cnt[j];
}

// ---------------------------------------------------------------- K2: per-bin scan + starts
__global__ __launch_bounds__(256) void binscan_starts_kernel(
    int* __restrict__ bc, int n_genes, int* __restrict__ totals,
    int* __restrict__ starts, int* __restrict__ done, int nblocks) {
  __shared__ int s_amlast;
  __shared__ int s_ws[4];
  int lane = threadIdx.x & 63;
  int wv = threadIdx.x >> 6;               // 0..3
  int bin = blockIdx.x * 4 + wv;
  if (bin < n_genes) {
    int2* row = (int2*)(bc + (size_t)bin * NB);   // 64 int2 per row
    int2 v = row[lane];
    int p = v.x + v.y;
    int ip = p;
#pragma unroll
    for (int off = 1; off < 64; off <<= 1) {
      int q = __shfl_up(ip, off);
      if (lane >= off) ip += q;
    }
    int base = ip - p;                      // exclusive prefix of this lane's pair
    int2 e;
    e.x = base;
    e.y = base + v.x;
    row[lane] = e;
    if (lane == 63) totals[bin] = ip;
  }
  __syncthreads();
  if (threadIdx.x == 0) {
    __threadfence();                        // publish totals
    int tk = atomicAdd(done, 1);
    s_amlast = (tk == nblocks - 1);
  }
  __syncthreads();
  if (!s_amlast) return;
  __threadfence();                          // acquire all totals
  int t = threadIdx.x;
  int4 v = make_int4(0, 0, 0, 0);
  if (4 * t < n_genes) v = ((const int4*)totals)[t];
  int p = v.x + v.y + v.z + v.w;
  int ip = p;
#pragma unroll
  for (int off = 1; off < 64; off <<= 1) {
    int q = __shfl_up(ip, off);
    if (lane >= off) ip += q;
  }
  if (lane == 63) s_ws[wv] = ip;
  __syncthreads();
  int add = 0;
#pragma unroll
  for (int i = 0; i < 4; ++i)
    if (i < wv) add += s_ws[i];
  int excl = add + ip - p;
  int4 e;
  e.x = excl;
  e.y = excl + v.x;
  e.z = e.y + v.y;
  e.w = e.z + v.z;
  if (4 * t < n_genes) ((int4*)starts)[t] = e;
  if (4 * t + 4 == n_genes) starts[n_genes] = e.w + v.w;   // grand total
}

// ---------------------------------------------------------------- K3: scatter by gene
__global__ __launch_bounds__(256) void blockscatter_kernel(
    const int* __restrict__ gm, int F, int chunk,
    const int* __restrict__ bc, const int* __restrict__ starts,
    int* __restrict__ order, int n_genes) {
  __shared__ int cur[1000];
  int b = blockIdx.x;
  for (int j = threadIdx.x; j < n_genes; j += blockDim.x)
    cur[j] = starts[j] + bc[j * NB + b];
  __syncthreads();
  int lo = b * chunk;
  int hi = min(F, lo + chunk);
  for (int i = lo + threadIdx.x; i < hi; i += blockDim.x) {
    int g = gm[i];
    int p = atomicAdd(&cur[g], 1);
    order[p] = i;
  }
}

// ---------------------------------------------------------------- K4: embed + RAW pool
// One block per gene; W row staged in LDS, repacked k-contiguous (5 broadcast
// ds_read_b128 + 20 FMA per k). NEW: the computed x row is pooled immediately
// (atomicAdd of x.w into out) — deletes K5's 200k-fragment loop. Grouped
// fragments get the (o - x).w correction in K5 (delta-pool, exact).
__global__ __launch_bounds__(256) void embed_kernel(
    const float2* __restrict__ coords, const int* __restrict__ order,
    const int* __restrict__ starts, const float* __restrict__ W,
    float* __restrict__ emb, int n_genes,
    const int* __restrict__ lci, const int* __restrict__ genes_oi,
    const float* __restrict__ wexpr, float* __restrict__ out) {
  __shared__ float s_w[1000];
  __shared__ float s_freq[NFREQ];
  const int tid = threadIdx.x;
  if (tid < NFREQ)
    s_freq[tid] = exp2f(-0.39863137f * (float)(tid + 1));
  int g = blockIdx.x;
  const float* __restrict__ Wg = W + (size_t)g * (4 * NFREQ * DD);
  for (int idx = tid; idx < 1000; idx += blockDim.x) {
    int k = idx / 20, r = idx % 20;
    s_w[idx] = (r < 10) ? Wg[10 * k + r] : Wg[500 + 10 * k + (r - 10)];
  }
  __syncthreads();
  int s0 = starts[g];
  int s1 = starts[g + 1];
  const float4* __restrict__ w4 = (const float4*)s_w;

  for (int i = s0 + tid; i < s1; i += blockDim.x) {
    int f = order[i];
    float2 xy = coords[f];
    float a0 = 0.f, a1 = 0.f, a2 = 0.f, a3 = 0.f, a4 = 0.f;
#pragma unroll 2
    for (int k = 0; k < NFREQ; ++k) {
      float fr = s_freq[k];
      float ax = xy.x * fr;
      float ay = xy.y * fr;
      float sx = __sinf(ax), cx = __cosf(ax);
      float sy = __sinf(ay), cy = __cosf(ay);
      float4 c0 = w4[5 * k + 0];   // e0..e3   = w0s[0..3]
      float4 c1 = w4[5 * k + 1];   // e4..e7   = w0s[4], w0c[0..2]
      float4 c2 = w4[5 * k + 2];   // e8..e11  = w0c[3..4], w1s[0..1]
      float4 c3 = w4[5 * k + 3];   // e12..e15 = w1s[2..4], w1c[0]
      float4 c4 = w4[5 * k + 4];   // e16..e19 = w1c[1..4]
      a0 += sx * c0.x + cx * c1.y + sy * c2.z + cy * c3.w;
      a1 += sx * c0.y + cx * c1.z + sy * c2.w + cy * c4.x;
      a2 += sx * c0.z + cx * c1.w + sy * c3.x + cy * c4.y;
      a3 += sx * c0.w + cx * c2.x + sy * c3.y + cy * c4.z;
      a4 += sx * c1.x + cx * c2.y + sy * c3.z + cy * c4.w;
    }
    float x0 = 1.f / (1.f + __expf(-a0));
    float x1 = 1.f / (1.f + __expf(-a1));
    float x2 = 1.f / (1.f + __expf(-a2));
    float x3 = 1.f / (1.f + __expf(-a3));
    float x4 = 1.f / (1.f + __expf(-a4));
    float* e = emb + (size_t)f * EST;
    float4 r;
    r.x = x0; r.y = x1; r.z = x2; r.w = x3;
    *reinterpret_cast<float4*>(e) = r;
    e[4] = x4;
    // raw pool: out[ix] += x . wexpr[genes_oi[ix % n_genes]]
    int ix = lci[f];
    const float* w = wexpr + (size_t)genes_oi[ix % n_genes] * DD;
    float s = x0 * w[0] + x1 * w[1] + x2 * w[2] + x3 * w[3] + x4 * w[4];
    atomicAdd(out + ix, s);
  }
}

// ---------------------------------------------------------------- attention group, DELTA pool
template <int SZ>
__device__ __forceinline__ void attn_group_delta(const int* __restrict__ idx,
                                                 const float* __restrict__ emb,
                                                 const int* __restrict__ lci,
                                                 const int* __restrict__ genes_oi,
                                                 const float* __restrict__ wexpr,
                                                 int n_genes, float* __restrict__ out) {
  int fid[SZ];
  float x[SZ][DD];
#pragma unroll
  for (int a = 0; a < SZ; ++a) {
    fid[a] = idx[a];
    const float* p = emb + (size_t)fid[a] * EST;
    float4 v = *reinterpret_cast<const float4*>(p);
    x[a][0] = v.x; x[a][1] = v.y; x[a][2] = v.z; x[a][3] = v.w;
    x[a][4] = p[4];
  }
  const float scale = rsqrtf((float)SZ);   // reference scales by sqrt(seq_len)
#pragma unroll
  for (int a = 0; a < SZ; ++a) {
    float sc[SZ];
    float m = -1e30f;
#pragma unroll
    for (int b = 0; b < SZ; ++b) {
      float dt = 0.f;
#pragma unroll
      for (int d = 0; d < DD; ++d) dt += x[a][d] * x[b][d];
      sc[b] = dt * scale;
      m = fmaxf(m, sc[b]);
    }
    float sum = 0.f;
#pragma unroll
    for (int b = 0; b < SZ; ++b) {
      sc[b] = __expf(sc[b] - m);
      sum += sc[b];
    }
    float inv = 1.f / sum;
    int ix = lci[fid[a]];
    int g = genes_oi[ix % n_genes];
    const float* w = wexpr + (size_t)g * DD;
    float s = 0.f;
#pragma unroll
    for (int d = 0; d < DD; ++d) {
      float acc = 0.f;
#pragma unroll
      for (int b = 0; b < SZ; ++b) acc += sc[b] * x[b][d];
      s += (acc * inv - x[a][d]) * w[d];
    }
    atomicAdd(out + ix, s);
  }
}

// ---------------------------------------------------------------- K5: group deltas only
__global__ __launch_bounds__(256) void attn_delta_kernel(
    const int* __restrict__ n2, int g2,
    const int* __restrict__ n3, int g3,
    const int* __restrict__ n4, int g4,
    const float* __restrict__ emb, const int* __restrict__ lci,
    const int* __restrict__ genes_oi, const float* __restrict__ wexpr,
    int n_genes, float* __restrict__ out) {
  int gtid = blockIdx.x * blockDim.x + threadIdx.x;
  int gs = gridDim.x * blockDim.x;
  int gtot = g2 + g3 + g4;
  for (int w = gtid; w < gtot; w += gs) {
    if (w < g2)
      attn_group_delta<2>(n2 + (size_t)w * 2, emb, lci, genes_oi, wexpr, n_genes, out);
    else if (w < g2 + g3)
      attn_group_delta<3>(n3 + (size_t)(w - g2) * 3, emb, lci, genes_oi, wexpr, n_genes, out);
    else
      attn_group_delta<4>(n4 + (size_t)(w - g2 - g3) * 4, emb, lci, genes_oi, wexpr, n_genes, out);
  }
}

// ---------------------------------------------------------------- launch
extern "C" void kernel_launch(void* const* d_in, const int* in_sizes, int n_in,
                              void* d_out, int out_size, void* d_ws, size_t ws_size,
                              hipStream_t stream) {
  const float2* coords  = (const float2*)d_in[0];
  const int* gm         = (const int*)d_in[1];
  const int* n2         = (const int*)d_in[2];
  const int* n3         = (const int*)d_in[3];
  const int* n4         = (const int*)d_in[4];
  const int* lci        = (const int*)d_in[5];
  const int* genes_oi   = (const int*)d_in[6];
  const float* W        = (const float*)d_in[7];
  const float* wexpr    = (const float*)d_in[8];
  const float* bias     = (const float*)d_in[9];
  float* out            = (float*)d_out;

  const int F       = in_sizes[1];
  const int n_genes = in_sizes[6];
  const int g2 = in_sizes[2] / 2;
  const int g3 = in_sizes[3] / 3;
  const int g4 = in_sizes[4] / 4;

  char* ws = (char*)d_ws;
  size_t off = 0;
  float* emb   = (float*)(ws + off); off += (size_t)F * EST * sizeof(float);
  int* order   = (int*)(ws + off);   off += (size_t)F * sizeof(int);
  int* bc      = (int*)(ws + off);   off += (size_t)n_genes * NB * sizeof(int);
  off = (off + 15) & ~(size_t)15;
  int* starts  = (int*)(ws + off);   off += (size_t)(n_genes + 4) * sizeof(int);
  off = (off + 15) & ~(size_t)15;
  int* totals  = (int*)(ws + off);   off += (size_t)n_genes * sizeof(int);
  int* done    = (int*)(ws + off);   off += 4 * sizeof(int);

  const int tb = 256;
  const int chunk = (F + NB - 1) / NB;
  const int n_cells = out_size / n_genes;   // out_size in floats

  hist_init_kernel<<<1024, tb, 0, stream>>>(gm, F, chunk, bc, n_genes, done,
                                            out, bias, genes_oi, n_cells);
  int scan_blocks = (n_genes + 3) / 4;    // one wave per bin, 4 bins/block
  binscan_starts_kernel<<<scan_blocks, tb, 0, stream>>>(bc, n_genes, totals,
                                                        starts, done, scan_blocks);
  blockscatter_kernel<<<NB, tb, 0, stream>>>(gm, F, chunk, bc, starts, order, n_genes);
  embed_kernel<<<n_genes, tb, 0, stream>>>(coords, order, starts, W, emb, n_genes,
                                           lci, genes_oi, wexpr, out);
  attn_delta_kernel<<<512, tb, 0, stream>>>(n2, g2, n3, g3, n4, g4,
                                            emb, lci, genes_oi, wexpr,
                                            n_genes, out);
}

// Round 7
// 135.758 us; speedup vs baseline: 5.3150x; 1.0167x over previous
//
#include <hip/hip_runtime.h>
#include <math.h>

#define DD 5          // embedding dim
#define EST 8         // emb row stride (padded 5 -> 8 floats, 32B rows)
#define NFREQ 50      // frequencies per coordinate
#define NB 128        // sort blocks
// ENC_DIM = 4*NFREQ = 200; W row per gene = 200*5 = 1000 floats
//
// Budget (r5 probe + r6): fills ~86us (harness, untouchable), embed+rawpool ~18,
// attn ~10, hist_init ~7, binscan ~3, scatter ~5, gaps ~8.
// r7: attn_delta one-thread-per-group -> one-thread-per-ROW (2.7x parallelism,
// SZ dots instead of SZ^2 per thread, same atomic multiset).

// ---------------------------------------------------------------- K1: hist + out-init
__global__ __launch_bounds__(256) void hist_init_kernel(
    const int* __restrict__ gm, int F, int chunk,
    int* __restrict__ bc, int n_genes, int* __restrict__ done,
    float* __restrict__ out, const float* __restrict__ bias,
    const int* __restrict__ genes_oi, int n_cells) {
  __shared__ int cnt[1000];
  __shared__ float s_brow[1000];
  const int tid = threadIdx.x;
  if (blockIdx.x == 0 && tid == 0) *done = 0;
  for (int j = tid; j < n_genes; j += blockDim.x) {
    s_brow[j] = bias[genes_oi[j]];
    cnt[j] = 0;
  }
  __syncthreads();
  if (blockIdx.x < NB) {
    int lo = blockIdx.x * chunk;
    int hi = min(F, lo + chunk);
    for (int i = lo + tid; i < hi; i += blockDim.x)
      atomicAdd(&cnt[gm[i]], 1);
  }
  // out <- bias row broadcast: pure float4 stores from LDS (n_genes % 4 == 0)
  const float4* b4 = (const float4*)s_brow;
  const int q = n_genes >> 2;          // 250 float4 per row
  for (int c = blockIdx.x; c < n_cells; c += gridDim.x) {
    float4* dst = (float4*)out + (size_t)c * q;
    for (int t = tid; t < q; t += blockDim.x) dst[t] = b4[t];
  }
  __syncthreads();
  if (blockIdx.x < NB)
    for (int j = tid; j < n_genes; j += blockDim.x)
      bc[j * NB + blockIdx.x] = cnt[j];
}

// ---------------------------------------------------------------- K2: per-bin scan + starts
__global__ __launch_bounds__(256) void binscan_starts_kernel(
    int* __restrict__ bc, int n_genes, int* __restrict__ totals,
    int* __restrict__ starts, int* __restrict__ done, int nblocks) {
  __shared__ int s_amlast;
  __shared__ int s_ws[4];
  int lane = threadIdx.x & 63;
  int wv = threadIdx.x >> 6;               // 0..3
  int bin = blockIdx.x * 4 + wv;
  if (bin < n_genes) {
    int2* row = (int2*)(bc + (size_t)bin * NB);   // 64 int2 per row
    int2 v = row[lane];
    int p = v.x + v.y;
    int ip = p;
#pragma unroll
    for (int off = 1; off < 64; off <<= 1) {
      int q = __shfl_up(ip, off);
      if (lane >= off) ip += q;
    }
    int base = ip - p;                      // exclusive prefix of this lane's pair
    int2 e;
    e.x = base;
    e.y = base + v.x;
    row[lane] = e;
    if (lane == 63) totals[bin] = ip;
  }
  __syncthreads();
  if (threadIdx.x == 0) {
    __threadfence();                        // publish totals
    int tk = atomicAdd(done, 1);
    s_amlast = (tk == nblocks - 1);
  }
  __syncthreads();
  if (!s_amlast) return;
  __threadfence();                          // acquire all totals
  int t = threadIdx.x;
  int4 v = make_int4(0, 0, 0, 0);
  if (4 * t < n_genes) v = ((const int4*)totals)[t];
  int p = v.x + v.y + v.z + v.w;
  int ip = p;
#pragma unroll
  for (int off = 1; off < 64; off <<= 1) {
    int q = __shfl_up(ip, off);
    if (lane >= off) ip += q;
  }
  if (lane == 63) s_ws[wv] = ip;
  __syncthreads();
  int add = 0;
#pragma unroll
  for (int i = 0; i < 4; ++i)
    if (i < wv) add += s_ws[i];
  int excl = add + ip - p;
  int4 e;
  e.x = excl;
  e.y = excl + v.x;
  e.z = e.y + v.y;
  e.w = e.z + v.z;
  if (4 * t < n_genes) ((int4*)starts)[t] = e;
  if (4 * t + 4 == n_genes) starts[n_genes] = e.w + v.w;   // grand total
}

// ---------------------------------------------------------------- K3: scatter by gene
__global__ __launch_bounds__(256) void blockscatter_kernel(
    const int* __restrict__ gm, int F, int chunk,
    const int* __restrict__ bc, const int* __restrict__ starts,
    int* __restrict__ order, int n_genes) {
  __shared__ int cur[1000];
  int b = blockIdx.x;
  for (int j = threadIdx.x; j < n_genes; j += blockDim.x)
    cur[j] = starts[j] + bc[j * NB + b];
  __syncthreads();
  int lo = b * chunk;
  int hi = min(F, lo + chunk);
  for (int i = lo + threadIdx.x; i < hi; i += blockDim.x) {
    int g = gm[i];
    int p = atomicAdd(&cur[g], 1);
    order[p] = i;
  }
}

// ---------------------------------------------------------------- K4: embed + RAW pool
// One block per gene; W row staged in LDS, repacked k-contiguous (5 broadcast
// ds_read_b128 + 20 FMA per k). Computed x row is pooled immediately (delta-pool
// split, exact): grouped fragments get (o - x).w correction in K5.
__global__ __launch_bounds__(256) void embed_kernel(
    const float2* __restrict__ coords, const int* __restrict__ order,
    const int* __restrict__ starts, const float* __restrict__ W,
    float* __restrict__ emb, int n_genes,
    const int* __restrict__ lci, const int* __restrict__ genes_oi,
    const float* __restrict__ wexpr, float* __restrict__ out) {
  __shared__ float s_w[1000];
  __shared__ float s_freq[NFREQ];
  const int tid = threadIdx.x;
  if (tid < NFREQ)
    s_freq[tid] = exp2f(-0.39863137f * (float)(tid + 1));
  int g = blockIdx.x;
  const float* __restrict__ Wg = W + (size_t)g * (4 * NFREQ * DD);
  for (int idx = tid; idx < 1000; idx += blockDim.x) {
    int k = idx / 20, r = idx % 20;
    s_w[idx] = (r < 10) ? Wg[10 * k + r] : Wg[500 + 10 * k + (r - 10)];
  }
  __syncthreads();
  int s0 = starts[g];
  int s1 = starts[g + 1];
  const float4* __restrict__ w4 = (const float4*)s_w;

  for (int i = s0 + tid; i < s1; i += blockDim.x) {
    int f = order[i];
    float2 xy = coords[f];
    float a0 = 0.f, a1 = 0.f, a2 = 0.f, a3 = 0.f, a4 = 0.f;
#pragma unroll 2
    for (int k = 0; k < NFREQ; ++k) {
      float fr = s_freq[k];
      float ax = xy.x * fr;
      float ay = xy.y * fr;
      float sx = __sinf(ax), cx = __cosf(ax);
      float sy = __sinf(ay), cy = __cosf(ay);
      float4 c0 = w4[5 * k + 0];   // e0..e3   = w0s[0..3]
      float4 c1 = w4[5 * k + 1];   // e4..e7   = w0s[4], w0c[0..2]
      float4 c2 = w4[5 * k + 2];   // e8..e11  = w0c[3..4], w1s[0..1]
      float4 c3 = w4[5 * k + 3];   // e12..e15 = w1s[2..4], w1c[0]
      float4 c4 = w4[5 * k + 4];   // e16..e19 = w1c[1..4]
      a0 += sx * c0.x + cx * c1.y + sy * c2.z + cy * c3.w;
      a1 += sx * c0.y + cx * c1.z + sy * c2.w + cy * c4.x;
      a2 += sx * c0.z + cx * c1.w + sy * c3.x + cy * c4.y;
      a3 += sx * c0.w + cx * c2.x + sy * c3.y + cy * c4.z;
      a4 += sx * c1.x + cx * c2.y + sy * c3.z + cy * c4.w;
    }
    float x0 = 1.f / (1.f + __expf(-a0));
    float x1 = 1.f / (1.f + __expf(-a1));
    float x2 = 1.f / (1.f + __expf(-a2));
    float x3 = 1.f / (1.f + __expf(-a3));
    float x4 = 1.f / (1.f + __expf(-a4));
    float* e = emb + (size_t)f * EST;
    float4 r;
    r.x = x0; r.y = x1; r.z = x2; r.w = x3;
    *reinterpret_cast<float4*>(e) = r;
    e[4] = x4;
    // raw pool: out[ix] += x . wexpr[genes_oi[ix % n_genes]]
    int ix = lci[f];
    const float* w = wexpr + (size_t)genes_oi[ix % n_genes] * DD;
    float s = x0 * w[0] + x1 * w[1] + x2 * w[2] + x3 * w[3] + x4 * w[4];
    atomicAdd(out + ix, s);
  }
}

// ---------------------------------------------------------------- attention ROW delta
// One thread per group MEMBER: loads the group's SZ emb rows (L1-broadcast
// with neighbors), computes only its own softmax row (SZ dots, not SZ^2),
// adds (o_a - x_a).w to out. Same atomic multiset as the per-group version.
template <int SZ>
__device__ __forceinline__ void attn_row_delta(const int* __restrict__ grp,
                                               int a,
                                               const float* __restrict__ emb,
                                               const int* __restrict__ lci,
                                               const int* __restrict__ genes_oi,
                                               const float* __restrict__ wexpr,
                                               int n_genes, float* __restrict__ out) {
  int fid[SZ];
  float x[SZ][DD];
#pragma unroll
  for (int b = 0; b < SZ; ++b) {
    fid[b] = grp[b];
    const float* p = emb + (size_t)fid[b] * EST;
    float4 v = *reinterpret_cast<const float4*>(p);
    x[b][0] = v.x; x[b][1] = v.y; x[b][2] = v.z; x[b][3] = v.w;
    x[b][4] = p[4];
  }
  const float scale = rsqrtf((float)SZ);   // reference scales by sqrt(seq_len)
  float sc[SZ];
  float m = -1e30f;
#pragma unroll
  for (int b = 0; b < SZ; ++b) {
    float dt = 0.f;
#pragma unroll
    for (int d = 0; d < DD; ++d) dt += x[a][d] * x[b][d];
    sc[b] = dt * scale;
    m = fmaxf(m, sc[b]);
  }
  float sum = 0.f;
#pragma unroll
  for (int b = 0; b < SZ; ++b) {
    sc[b] = __expf(sc[b] - m);
    sum += sc[b];
  }
  float inv = 1.f / sum;
  int ix = lci[fid[a]];
  int g = genes_oi[ix % n_genes];
  const float* w = wexpr + (size_t)g * DD;
  float s = 0.f;
#pragma unroll
  for (int d = 0; d < DD; ++d) {
    float acc = 0.f;
#pragma unroll
    for (int b = 0; b < SZ; ++b) acc += sc[b] * x[b][d];
    s += (acc * inv - x[a][d]) * w[d];
  }
  atomicAdd(out + ix, s);
}

// ---------------------------------------------------------------- K5: group row deltas
// Row index space: [0,c2) pairs, [c2,c2+c3) triples, rest quads.
__global__ __launch_bounds__(256) void attn_delta_kernel(
    const int* __restrict__ n2, int c2,
    const int* __restrict__ n3, int c3,
    const int* __restrict__ n4, int c4,
    const float* __restrict__ emb, const int* __restrict__ lci,
    const int* __restrict__ genes_oi, const float* __restrict__ wexpr,
    int n_genes, float* __restrict__ out) {
  int gtid = blockIdx.x * blockDim.x + threadIdx.x;
  int gs = gridDim.x * blockDim.x;
  int rtot = c2 + c3 + c4;
  for (int r = gtid; r < rtot; r += gs) {
    if (r < c2) {
      int rb = r & ~1;
      attn_row_delta<2>(n2 + rb, r & 1, emb, lci, genes_oi, wexpr, n_genes, out);
    } else if (r < c2 + c3) {
      unsigned rp = (unsigned)(r - c2);
      unsigned grp = rp / 3u;                 // magic-mul
      int a = (int)(rp - grp * 3u);
      attn_row_delta<3>(n3 + grp * 3u, a, emb, lci, genes_oi, wexpr, n_genes, out);
    } else {
      int rp = r - c2 - c3;
      int rb = rp & ~3;
      attn_row_delta<4>(n4 + rb, rp & 3, emb, lci, genes_oi, wexpr, n_genes, out);
    }
  }
}

// ---------------------------------------------------------------- launch
extern "C" void kernel_launch(void* const* d_in, const int* in_sizes, int n_in,
                              void* d_out, int out_size, void* d_ws, size_t ws_size,
                              hipStream_t stream) {
  const float2* coords  = (const float2*)d_in[0];
  const int* gm         = (const int*)d_in[1];
  const int* n2         = (const int*)d_in[2];
  const int* n3         = (const int*)d_in[3];
  const int* n4         = (const int*)d_in[4];
  const int* lci        = (const int*)d_in[5];
  const int* genes_oi   = (const int*)d_in[6];
  const float* W        = (const float*)d_in[7];
  const float* wexpr    = (const float*)d_in[8];
  const float* bias     = (const float*)d_in[9];
  float* out            = (float*)d_out;

  const int F       = in_sizes[1];
  const int n_genes = in_sizes[6];
  const int c2 = in_sizes[2];
  const int c3 = in_sizes[3];
  const int c4 = in_sizes[4];

  char* ws = (char*)d_ws;
  size_t off = 0;
  float* emb   = (float*)(ws + off); off += (size_t)F * EST * sizeof(float);
  int* order   = (int*)(ws + off);   off += (size_t)F * sizeof(int);
  int* bc      = (int*)(ws + off);   off += (size_t)n_genes * NB * sizeof(int);
  off = (off + 15) & ~(size_t)15;
  int* starts  = (int*)(ws + off);   off += (size_t)(n_genes + 4) * sizeof(int);
  off = (off + 15) & ~(size_t)15;
  int* totals  = (int*)(ws + off);   off += (size_t)n_genes * sizeof(int);
  int* done    = (int*)(ws + off);   off += 4 * sizeof(int);

  const int tb = 256;
  const int chunk = (F + NB - 1) / NB;
  const int n_cells = out_size / n_genes;   // out_size in floats

  hist_init_kernel<<<1024, tb, 0, stream>>>(gm, F, chunk, bc, n_genes, done,
                                            out, bias, genes_oi, n_cells);
  int scan_blocks = (n_genes + 3) / 4;    // one wave per bin, 4 bins/block
  binscan_starts_kernel<<<scan_blocks, tb, 0, stream>>>(bc, n_genes, totals,
                                                        starts, done, scan_blocks);
  blockscatter_kernel<<<NB, tb, 0, stream>>>(gm, F, chunk, bc, starts, order, n_genes);
  embed_kernel<<<n_genes, tb, 0, stream>>>(coords, order, starts, W, emb, n_genes,
                                           lci, genes_oi, wexpr, out);
  int rtot = c2 + c3 + c4;
  int ablocks = (rtot + tb - 1) / tb;
  attn_delta_kernel<<<ablocks, tb, 0, stream>>>(n2, c2, n3, c3, n4, c4,
                                                emb, lci, genes_oi, wexpr,
                                                n_genes, out);
}